// Round 2
// baseline (29653.644 us; speedup 1.0000x reference)
//
#include <hip/hip_runtime.h>
#include <hip/hip_bf16.h>

using bf16 = __hip_bfloat16;

#define B_   16
#define C_   768
#define NP_  196
#define H_   12
#define HD_  64
#define NPNP 38416   // 196*196

// Dual-dtype input load: harness may present inputs as bf16 or fp32.
// isbf flag is computed on-device by k_probe each launch.
static __device__ __forceinline__ float ldin(const void* p, size_t i, int isbf) {
    return isbf ? __bfloat162float(((const bf16*)p)[i]) : ((const float*)p)[i];
}

// Probe: read first 4096 elements of patch_w as bf16. Real bf16 weights have
// |x| < ~0.1; fp32 data misread as bf16 yields huge values (random exponent).
__global__ __launch_bounds__(256)
void k_probe(const void* w, int* flag)
{
    __shared__ float sm[256];
    float mx = 0.f;
    for (int i = threadIdx.x; i < 4096; i += 256)
        mx = fmaxf(mx, fabsf(__bfloat162float(((const bf16*)w)[i])));
    sm[threadIdx.x] = mx;
    __syncthreads();
    for (int s = 128; s > 0; s >>= 1) {
        if (threadIdx.x < s) sm[threadIdx.x] = fmaxf(sm[threadIdx.x], sm[threadIdx.x + s]);
        __syncthreads();
    }
    if (threadIdx.x == 0) flag[0] = (sm[0] < 1e4f) ? 1 : 0;   // 1 = inputs are bf16
}

// ---------------------------------------------------------------------------
// Generic GEMM: C[m,n] = act( sum_k A[m,k]*W[n,k] + bias[n] )
// A fp32 [M x K] row stride lda; W input-dtype [N x K] row-major; bias [N].
// act: 0 = none, 1 = exact GELU. K must be a multiple of 16.
// ---------------------------------------------------------------------------
__global__ __launch_bounds__(256)
void k_gemm(const float* __restrict__ A, int lda,
            const void* __restrict__ W, const void* __restrict__ bias,
            float* __restrict__ Cout, int M, int N, int K, int act,
            const int* __restrict__ flg)
{
    const int isbf = flg[0];
    __shared__ float As[16][65];
    __shared__ float Ws[16][65];
    int tid = threadIdx.x;
    int tx = tid & 15, ty = tid >> 4;
    int bn = blockIdx.x * 64, bm = blockIdx.y * 64;
    float acc[4][4] = {};
    for (int k0 = 0; k0 < K; k0 += 16) {
        for (int i = tid; i < 16 * 64; i += 256) {
            int kk = i >> 6, r = i & 63;
            int gm = bm + r, gk = k0 + kk;
            As[kk][r] = (gm < M) ? A[(size_t)gm * lda + gk] : 0.f;
            int gn = bn + r;
            Ws[kk][r] = (gn < N) ? ldin(W, (size_t)gn * K + gk, isbf) : 0.f;
        }
        __syncthreads();
#pragma unroll
        for (int kk = 0; kk < 16; ++kk) {
            float a[4], w[4];
#pragma unroll
            for (int i = 0; i < 4; i++) a[i] = As[kk][ty * 4 + i];
#pragma unroll
            for (int j = 0; j < 4; j++) w[j] = Ws[kk][tx * 4 + j];
#pragma unroll
            for (int i = 0; i < 4; i++)
#pragma unroll
                for (int j = 0; j < 4; j++)
                    acc[i][j] += a[i] * w[j];
        }
        __syncthreads();
    }
#pragma unroll
    for (int i = 0; i < 4; i++) {
        int gm = bm + ty * 4 + i;
        if (gm >= M) continue;
#pragma unroll
        for (int j = 0; j < 4; j++) {
            int gn = bn + tx * 4 + j;
            if (gn >= N) continue;
            float v = acc[i][j] + ldin(bias, gn, isbf);
            if (act == 1) v = 0.5f * v * (1.0f + erff(v * 0.70710678118654752f));
            Cout[(size_t)gm * N + gn] = v;
        }
    }
}

// ---------------------------------------------------------------------------
// Patch gather: p[b, n, k] = x[b, c, gy*16+py, gx*16+px], k = c*256+py*16+px
// ---------------------------------------------------------------------------
__global__ __launch_bounds__(256)
void k_patch_gather(const void* __restrict__ x, float* __restrict__ p,
                    const int* __restrict__ flg)
{
    const int isbf = flg[0];
    int idx = blockIdx.x * 256 + threadIdx.x;            // B*NP*768 = 2,408,448
    int k = idx % 768;
    int n = (idx / 768) % NP_;
    int b = idx / (768 * NP_);
    int c = k >> 8, r = k & 255;
    int py = r >> 4, px = r & 15;
    int gy = n / 14, gx = n % 14;
    int iy = gy * 16 + py, ix = gx * 16 + px;
    p[idx] = ldin(x, (((size_t)b * 3 + c) * 224 + iy) * 224 + ix, isbf);
}

__global__ __launch_bounds__(256)
void k_addpos(float* __restrict__ h, const void* __restrict__ pos,
              const int* __restrict__ flg)
{
    const int isbf = flg[0];
    int idx = blockIdx.x * 256 + threadIdx.x;            // 2,408,448
    h[idx] += ldin(pos, idx % (NP_ * C_), isbf);
}

// ---------------------------------------------------------------------------
// LayerNorm over C=768. One block (256 thr) per row.
// ---------------------------------------------------------------------------
__device__ __forceinline__ void ln_row(const float* __restrict__ x,
                                       const void* __restrict__ w,
                                       const void* __restrict__ b,
                                       float* __restrict__ y, int t,
                                       float* red, float* stat, int isbf)
{
    float a0 = x[t], a1 = x[t + 256], a2 = x[t + 512];
    float s = a0 + a1 + a2;
#pragma unroll
    for (int off = 32; off > 0; off >>= 1) s += __shfl_down(s, off);
    if ((t & 63) == 0) red[t >> 6] = s;
    __syncthreads();
    if (t == 0) stat[0] = (red[0] + red[1] + red[2] + red[3]) * (1.f / 768.f);
    __syncthreads();
    float m = stat[0];
    float d0 = a0 - m, d1 = a1 - m, d2 = a2 - m;
    float s2 = d0 * d0 + d1 * d1 + d2 * d2;
#pragma unroll
    for (int off = 32; off > 0; off >>= 1) s2 += __shfl_down(s2, off);
    if ((t & 63) == 0) red[t >> 6] = s2;
    __syncthreads();
    if (t == 0) stat[1] = rsqrtf((red[0] + red[1] + red[2] + red[3]) * (1.f / 768.f) + 1e-6f);
    __syncthreads();
    float r = stat[1];
    y[t]       = d0 * r * ldin(w, t, isbf)       + ldin(b, t, isbf);
    y[t + 256] = d1 * r * ldin(w, t + 256, isbf) + ldin(b, t + 256, isbf);
    y[t + 512] = d2 * r * ldin(w, t + 512, isbf) + ldin(b, t + 512, isbf);
}

__global__ __launch_bounds__(256)
void k_layernorm(const float* __restrict__ X, const void* __restrict__ w,
                 const void* __restrict__ b, float* __restrict__ Y,
                 const int* __restrict__ flg)
{
    __shared__ float red[4];
    __shared__ float stat[2];
    int row = blockIdx.x;
    ln_row(X + (size_t)row * C_, w, b, Y + (size_t)row * C_, threadIdx.x, red, stat, flg[0]);
}

// LN of concat([cls, h]) without materializing the concat. rows = B*197.
__global__ __launch_bounds__(256)
void k_layernorm_cat(const float* __restrict__ cls, const float* __restrict__ h,
                     const void* __restrict__ w, const void* __restrict__ b,
                     float* __restrict__ Y, const int* __restrict__ flg)
{
    __shared__ float red[4];
    __shared__ float stat[2];
    int row = blockIdx.x;
    int bb = row / 197, tkn = row % 197;
    const float* src = (tkn == 0) ? (cls + (size_t)bb * C_)
                                  : (h + ((size_t)bb * NP_ + (tkn - 1)) * C_);
    ln_row(src, w, b, Y + (size_t)row * C_, threadIdx.x, red, stat, flg[0]);
}

// ---------------------------------------------------------------------------
// attn[b,h,n,m] = SCALE * sum_d q[b,n,h,d] * k[b,m,h,d]   (from qkv buffer)
// ---------------------------------------------------------------------------
__global__ __launch_bounds__(256)
void k_qk(const float* __restrict__ qkv, float* __restrict__ attn)
{
    __shared__ float qs[64];
    int blk = blockIdx.x;
    int n = blk % NP_;
    int hh = (blk / NP_) % H_;
    int b = blk / (NP_ * H_);
    if (threadIdx.x < 64)
        qs[threadIdx.x] = qkv[((size_t)b * NP_ + n) * 2304 + hh * 64 + threadIdx.x] * 0.125f;
    __syncthreads();
    int m = threadIdx.x;
    if (m < NP_) {
        const float* kp = qkv + ((size_t)b * NP_ + m) * 2304 + 768 + hh * 64;
        float s = 0.f;
#pragma unroll 8
        for (int d = 0; d < 64; d++) s += qs[d] * kp[d];
        attn[(((size_t)(b * H_ + hh)) * NP_ + n) * NP_ + m] = s;
    }
}

// IN-PLACE head mix: a[b,g,n,m] = sum_h a[b,h,n,m]*w[g,h] + bias[g].
// One thread per (b,n,m): reads all 12 heads into registers, writes back.
__global__ __launch_bounds__(256)
void k_headmix(float* __restrict__ a, const void* __restrict__ w,
               const void* __restrict__ bias, const int* __restrict__ flg)
{
    const int isbf = flg[0];
    __shared__ float ws_[144];
    __shared__ float bs_[12];
    int tid = threadIdx.x;
    if (tid < 144) ws_[tid] = ldin(w, tid, isbf);
    if (tid < 12) bs_[tid] = ldin(bias, tid, isbf);
    __syncthreads();
    int idx = blockIdx.x * 256 + tid;                    // B*38416 = 614,656
    int b = idx / NPNP, nm = idx % NPNP;
    float* p = a + (size_t)b * H_ * NPNP + nm;
    float v[12];
#pragma unroll
    for (int hh = 0; hh < 12; hh++) v[hh] = p[(size_t)hh * NPNP];
#pragma unroll
    for (int g = 0; g < 12; g++) {
        float acc = bs_[g];
#pragma unroll
        for (int hh = 0; hh < 12; hh++) acc += ws_[g * 12 + hh] * v[hh];
        p[(size_t)g * NPNP] = acc;
    }
}

// softmax over last axis (196); one wave per row
__global__ __launch_bounds__(64)
void k_softmax(float* __restrict__ attn)
{
    size_t row = blockIdx.x;                             // B*H*NP
    float* p = attn + row * NP_;
    int t = threadIdx.x;
    float v[4];
    float mx = -1e30f;
#pragma unroll
    for (int i = 0; i < 4; i++) {
        int m = t + 64 * i;
        v[i] = (m < NP_) ? p[m] : -1e30f;
        mx = fmaxf(mx, v[i]);
    }
#pragma unroll
    for (int off = 32; off > 0; off >>= 1) mx = fmaxf(mx, __shfl_down(mx, off));
    mx = __shfl(mx, 0);
    float s = 0.f;
#pragma unroll
    for (int i = 0; i < 4; i++) {
        int m = t + 64 * i;
        if (m < NP_) { v[i] = expf(v[i] - mx); s += v[i]; }
    }
#pragma unroll
    for (int off = 32; off > 0; off >>= 1) s += __shfl_down(s, off);
    s = __shfl(s, 0);
    float inv = 1.0f / s;
#pragma unroll
    for (int i = 0; i < 4; i++) {
        int m = t + 64 * i;
        if (m < NP_) p[m] = v[i] * inv;
    }
}

// o[b,n,h*64+d] = sum_m attn[b,h,n,m] * v[b,m,h,d]; one thread per (b,n,c)
__global__ __launch_bounds__(256)
void k_av(const float* __restrict__ attn, const float* __restrict__ qkv,
          float* __restrict__ o)
{
    int idx = blockIdx.x * 256 + threadIdx.x;            // 2,408,448
    int c = idx % C_;
    int n = (idx / C_) % NP_;
    int b = idx / (C_ * NP_);
    int hh = c >> 6;
    const float* arow = attn + (((size_t)(b * H_ + hh)) * NP_ + n) * NP_;
    const float* vcol = qkv + (size_t)b * NP_ * 2304 + 1536 + c;
    float acc = 0.f;
#pragma unroll 4
    for (int m = 0; m < NP_; m++) acc += arow[m] * vcol[(size_t)m * 2304];
    o[idx] = acc;
}

// dst[i] += g[i%C] * src[i]
__global__ __launch_bounds__(256)
void k_resadd(float* __restrict__ dst, const float* __restrict__ src,
              const void* __restrict__ g, int total, const int* __restrict__ flg)
{
    const int isbf = flg[0];
    int i = blockIdx.x * 256 + threadIdx.x;
    if (i < total) dst[i] += ldin(g, i % C_, isbf) * src[i];
}

// class-attention: q[B,C], k/v [B*197,C] -> o[B,C]; one block per (b,h)
__global__ __launch_bounds__(256)
void k_ca_attn(const float* __restrict__ q, const float* __restrict__ kb,
               const float* __restrict__ vb, float* __restrict__ o)
{
    __shared__ float sc[200];
    __shared__ float qs[64];
    __shared__ float inv_s;
    int b = blockIdx.x / H_, hh = blockIdx.x % H_;
    int t = threadIdx.x;
    if (t < 64) qs[t] = q[b * C_ + hh * 64 + t] * 0.125f;
    __syncthreads();
    if (t < 197) {
        const float* kp = kb + ((size_t)b * 197 + t) * C_ + hh * 64;
        float s = 0.f;
#pragma unroll 8
        for (int d = 0; d < 64; d++) s += qs[d] * kp[d];
        sc[t] = s;
    }
    __syncthreads();
    if (t == 0) {
        float mx = -1e30f;
        for (int m = 0; m < 197; m++) mx = fmaxf(mx, sc[m]);
        float sum = 0.f;
        for (int m = 0; m < 197; m++) { float e = expf(sc[m] - mx); sc[m] = e; sum += e; }
        inv_s = 1.0f / sum;
    }
    __syncthreads();
    if (t < 64) {
        const float* vp = vb + (size_t)b * 197 * C_ + hh * 64 + t;
        float acc = 0.f;
        for (int m = 0; m < 197; m++) acc += sc[m] * vp[(size_t)m * C_];
        o[b * C_ + hh * 64 + t] = acc * inv_s;
    }
}

__global__ __launch_bounds__(256)
void k_bcast_cls(const void* __restrict__ ct, float* __restrict__ cls,
                 const int* __restrict__ flg)
{
    const int isbf = flg[0];
    int i = blockIdx.x * 256 + threadIdx.x;              // 16*768 = 12288
    if (i < B_ * C_) cls[i] = ldin(ct, i % C_, isbf);
}

__global__ __launch_bounds__(256)
void k_store_out(const float* __restrict__ src, void* __restrict__ dst, int n,
                 const int* __restrict__ flg)
{
    const int isbf = flg[0];
    int i = blockIdx.x * 256 + threadIdx.x;
    if (i < n) {
        if (isbf) ((bf16*)dst)[i] = __float2bfloat16(src[i]);
        else      ((float*)dst)[i] = src[i];
    }
}

// ---------------------------------------------------------------------------
extern "C" void kernel_launch(void* const* d_in, const int* in_sizes, int n_in,
                              void* d_out, int out_size, void* d_ws, size_t ws_size,
                              hipStream_t stream)
{
    const void* in_x     = d_in[0];
    const void* patch_w  = d_in[1];
    const void* patch_b  = d_in[2];
    const void* cls_tok  = d_in[3];
    const void* pos_emb  = d_in[4];
    const bf16* n1w = (const bf16*)d_in[5],  *n1b = (const bf16*)d_in[6];
    const bf16* qkvw = (const bf16*)d_in[7], *qkvb = (const bf16*)d_in[8];
    const bf16* plw = (const bf16*)d_in[9],  *plb = (const bf16*)d_in[10];
    const bf16* pww = (const bf16*)d_in[11], *pwb = (const bf16*)d_in[12];
    const bf16* projw = (const bf16*)d_in[13], *projb = (const bf16*)d_in[14];
    const bf16* n2w = (const bf16*)d_in[15], *n2b = (const bf16*)d_in[16];
    const bf16* f1w = (const bf16*)d_in[17], *f1b = (const bf16*)d_in[18];
    const bf16* f2w = (const bf16*)d_in[19], *f2b = (const bf16*)d_in[20];
    const bf16* g1 = (const bf16*)d_in[21],  *g2 = (const bf16*)d_in[22];
    const bf16* tn1w = (const bf16*)d_in[23], *tn1b = (const bf16*)d_in[24];
    const bf16* tqw = (const bf16*)d_in[25], *tqb = (const bf16*)d_in[26];
    const bf16* tkw = (const bf16*)d_in[27], *tkb = (const bf16*)d_in[28];
    const bf16* tvw = (const bf16*)d_in[29], *tvb = (const bf16*)d_in[30];
    const bf16* tprojw = (const bf16*)d_in[31], *tprojb = (const bf16*)d_in[32];
    const bf16* tn2w = (const bf16*)d_in[33], *tn2b = (const bf16*)d_in[34];
    const bf16* tf1w = (const bf16*)d_in[35], *tf1b = (const bf16*)d_in[36];
    const bf16* tf2w = (const bf16*)d_in[37], *tf2b = (const bf16*)d_in[38];
    const bf16* tg1 = (const bf16*)d_in[39], *tg2 = (const bf16*)d_in[40];
    const bf16* normw = (const bf16*)d_in[41], *normb = (const bf16*)d_in[42];
    const bf16* headw = (const bf16*)d_in[43], *headb = (const bf16*)d_in[44];
    (void)in_sizes; (void)n_in; (void)out_size; (void)ws_size;

    // Helper: byte offset for a bf16-vs-fp32 agnostic weight slice.
    // When inputs are bf16, element stride is 2 bytes; fp32 -> 4. We cannot
    // know on host, so we slice with ELEMENT indices on both candidate
    // pointers and let kernels pick. Trick: pass base + elem_off computed for
    // BOTH dtypes is impossible with one pointer, so instead slice by
    // byte offset = elem_off * (isbf?2:4)... Host doesn't know isbf.
    // Resolution: pass the ELEMENT offset separately? Simpler: compute both
    // byte offsets impossible -> pass base pointers + element offsets baked
    // into the index math. We do that by giving kernels the layer-sliced
    // pointer assuming bf16 AND fp32 variants... Instead: all per-layer
    // slices below are done with a macro that applies the offset inside the
    // kernel index (W pointer passed as char* with element offset folded into
    // the kernel's own indexing). To keep it simple we pass element-offset
    // pointers for BOTH dtypes via lambda closures at call time using the
    // byte size of the PROBED dtype -- but host can't probe. Final answer:
    // kernels receive the UNsliced base and a size_t element offset.
    // (see gemm lambda: it adds `woff` elements inside ldin index)

    const int M = B_ * NP_;          // 3136
    float* ws = (float*)d_ws;
    int* flg = (int*)d_ws;           // flag at ws[0]
    float* h  = ws + 256;            // 2,408,448
    float* y  = h + 2408448;         // 2,408,448
    float* S1 = y + 2408448;         // 9,633,792 (p / qkv / mlp hidden)
    float* S2 = S1 + 9633792;        // 7,375,872 (attn / proj-out / f2-out)
    // class-attention aliases
    float* u    = S1;                // 16*197*768 = 2,420,736
    float* kbuf = S1 + 2420736;
    float* vbuf = S1 + 4841472;      // ends 7,262,208 < 9,633,792
    float* cls  = S2;                // 12,288
    float* qbuf = S2 + 16384;
    float* ca_o = S2 + 32768;
    float* clsy = S2 + 49152;
    float* cmlp = S2 + 65536;        // 49,152
    float* outf = S2 + 131072;       // 16,000
    // total: 256 + 21,826,560 floats = 87.3 MB

    k_probe<<<1, 256, 0, stream>>>(patch_w, flg);

    // GEMM with element offsets folded host-side via typed pointer arithmetic
    // done INSIDE kernels: we pass void* base already sliced per-dtype is not
    // possible, so slice with bf16* arithmetic when flag==bf16 and float*
    // when fp32. Since host can't branch, we pass BYTE-agnostic: use bf16*
    // arithmetic for slicing and, in the fp32 case, the same ELEMENT offset
    // must be scaled 2x in bytes. ldin indexes elements from the base, so we
    // simply pass the UNsliced base plus an element offset argument.
    auto gemm = [&](const float* A, int lda, const void* Wbase, size_t weloff,
                    const void* Bbase, size_t beloff,
                    float* Cout, int Mm, int Nn, int Kk, int act) {
        dim3 g((Nn + 63) / 64, (Mm + 63) / 64);
        // fold element offsets by passing shifted element index via pointer
        // trickery is dtype-dependent; instead k_gemm indexes W at
        // (gn*K+gk) so we pre-add weloff by passing a shifted bf16* AND
        // relying on ldin to scale... that breaks for fp32. So: pass base
        // pointers shifted in ELEMENTS for both dtypes by giving k_gemm the
        // offset through an extra size_t pair? Cleaner: shift here for bf16
        // (2B) and fp32 (4B) can't coexist -> k_gemm takes explicit offsets.
        k_gemm<<<g, 256, 0, stream>>>(A, lda,
            Wbase, Bbase, Cout, Mm, Nn, Kk, act, flg);
        (void)weloff; (void)beloff;
    };

    // ---- patch embed -------------------------------------------------------
    k_patch_gather<<<9408, 256, 0, stream>>>(in_x, S1, flg);
    gemm(S1, 768, patch_w, 0, patch_b, 0, h, M, C_, 768, 0);
    k_addpos<<<9408, 256, 0, stream>>>(h, pos_emb, flg);

    // Per-layer slices: element offsets are dtype-independent, but BYTE
    // offsets differ. We slice with bf16* arithmetic; if inputs turn out to
    // be fp32, a bf16*-sliced pointer is wrong. Therefore all per-layer
    // slicing below uses a macro producing a void* at ELEMENT offset `o`
    // under BOTH dtypes -- impossible with one pointer unless we pass the
    // element offset into the kernel. We do exactly that for k_gemm-family
    // by giving each call a base pointer pre-shifted under the bf16
    // assumption AND, for the fp32 case, the same pointer arithmetic done on
    // float*. Since the flag decides inside the kernel, we must pass BOTH
    // candidate pointers. Small helper:
    #define SL(base, elo) (const void*)((const char*)(base)), (size_t)(elo)

    // To keep kernel signatures simple, per-layer kernels below receive the
    // BASE pointer and compute their own element offset from layer index L.
    // (k_gemm W/bias offsets are folded into N*K indexing by passing
    //  sliced-by-element pointers through two variants chosen in-kernel.)
    #undef SL

    // ---- 12 talking-heads blocks ------------------------------------------
    for (int L = 0; L < 12; L++) {
        // NOTE: per-layer weight slicing must be dtype-aware. We create both
        // bf16 and fp32 sliced pointers; kernels pick via flag by receiving
        // both. k_gemm takes W2/bias2 as the fp32-candidate.
        const bf16*  qw_b = qkvw + (size_t)L * 2304 * C_;
        const float* qw_f = (const float*)d_in[7] + (size_t)L * 2304 * C_;
        (void)qw_f;
        // ldin() indexes ELEMENTS from base, and element offsets are the
        // same for both dtypes -- but the POINTER passed must be the raw
        // base for the scaling to be correct under either dtype. So we pass
        // raw bases + fold the layer offset into the index by passing
        // (L-dependent) sliced pointers cast per-dtype inside kernels is
        // overkill. Simplest correct: since element offset is identical,
        // pass base and add offset in the kernel index -> k_gemm's W index
        // becomes woff + gn*K+gk. We reuse 'act' packing? No -- dedicated
        // wrapper kernels would bloat. We instead accept ONE extra launch
        // trick: pointers sliced as bf16* are correct when isbf=1; when
        // isbf=0 the same BYTE offset corresponds to HALF the element
        // offset, so fp32 reads would be wrong. Hence we must not slice.
        // => We pass raw bases with an element-offset argument. k_gemm was
        // declared without it, so we wrap via lambda captures below using
        // cudaKernel parameter... Simplest: call k_gemm with W pointer
        // adjusted in BYTES for bf16 and rely on flag? NO.
        break;
    }
    // The loop above intentionally does nothing: see k_gemm2 below.
    // ---- (real implementation continues) ----------------------------------

    // Re-do with offset-carrying launches:
    auto gemm2 = [&](const float* A, int lda, const void* W, size_t wo,
                     const void* bias, size_t bo, float* Cout,
                     int Mm, int Nn, int Kk, int act) {
        dim3 g((Nn + 63) / 64, (Mm + 63) / 64);
        // pass offsets by pointer-shifting per dtype inside kernel: we embed
        // offsets into the last two params of k_gemm2.
        extern __global__ void k_gemm2(const float*, int, const void*, size_t,
                                       const void*, size_t, float*, int, int,
                                       int, int, const int*);
        k_gemm2<<<g, 256, 0, stream>>>(A, lda, W, wo, bias, bo, Cout,
                                       Mm, Nn, Kk, act, flg);
    };

    for (int L = 0; L < 12; L++) {
        k_layernorm<<<M, 256, 0, stream>>>(h, (const char*)d_in[5] + 0, (const char*)d_in[6], y, flg);
        // ^ placeholder replaced below
        break;
    }

    // ---- actual pipeline (offset-aware) -----------------------------------
    // (see k_layernorm2 etc. definitions after kernel_launch)
    extern __global__ void k_layernorm2(const float*, const void*, size_t,
                                        const void*, size_t, float*, const int*);
    extern __global__ void k_layernorm_cat2(const float*, const float*,
                                            const void*, size_t, const void*, size_t,
                                            float*, const int*);
    extern __global__ void k_headmix2(float*, const void*, size_t,
                                      const void*, size_t, const int*);
    extern __global__ void k_resadd2(float*, const float*, const void*, size_t,
                                     int, const int*);

    for (int L = 0; L < 12; L++) {
        size_t lC = (size_t)L * C_;
        k_layernorm2<<<M, 256, 0, stream>>>(h, d_in[5], lC, d_in[6], lC, y, flg);
        gemm2(y, C_, d_in[7], (size_t)L * 2304 * C_, d_in[8], (size_t)L * 2304,
              S1, M, 2304, C_, 0);
        k_qk<<<B_ * H_ * NP_, 256, 0, stream>>>(S1, S2);
        k_headmix2<<<2401, 256, 0, stream>>>(S2, d_in[9], (size_t)L * 144,
                                             d_in[10], (size_t)L * 12, flg);
        k_softmax<<<B_ * H_ * NP_, 64, 0, stream>>>(S2);
        k_headmix2<<<2401, 256, 0, stream>>>(S2, d_in[11], (size_t)L * 144,
                                             d_in[12], (size_t)L * 12, flg);
        k_av<<<9408, 256, 0, stream>>>(S2, S1, y);
        gemm2(y, C_, d_in[13], (size_t)L * C_ * C_, d_in[14], lC, S2, M, C_, C_, 0);
        k_resadd2<<<9408, 256, 0, stream>>>(h, S2, d_in[21], lC, M * C_, flg);
        k_layernorm2<<<M, 256, 0, stream>>>(h, d_in[15], lC, d_in[16], lC, y, flg);
        gemm2(y, C_, d_in[17], (size_t)L * 3072 * C_, d_in[18], (size_t)L * 3072,
              S1, M, 3072, C_, 1);
        gemm2(S1, 3072, d_in[19], (size_t)L * C_ * 3072, d_in[20], lC, S2, M, C_, 3072, 0);
        k_resadd2<<<9408, 256, 0, stream>>>(h, S2, d_in[22], lC, M * C_, flg);
    }

    // ---- 2 class-attention blocks -----------------------------------------
    k_bcast_cls<<<48, 256, 0, stream>>>(cls_tok, cls, flg);
    const int Mu = B_ * 197;         // 3152
    for (int t = 0; t < 2; t++) {
        size_t tC = (size_t)t * C_;
        k_layernorm_cat2<<<Mu, 256, 0, stream>>>(cls, h, d_in[23], tC, d_in[24], tC, u, flg);
        gemm2(u, 197 * C_, d_in[25], (size_t)t * C_ * C_, d_in[26], tC, qbuf, B_, C_, C_, 0);
        gemm2(u, C_, d_in[27], (size_t)t * C_ * C_, d_in[28], tC, kbuf, Mu, C_, C_, 0);
        gemm2(u, C_, d_in[29], (size_t)t * C_ * C_, d_in[30], tC, vbuf, Mu, C_, C_, 0);
        k_ca_attn<<<B_ * H_, 256, 0, stream>>>(qbuf, kbuf, vbuf, ca_o);
        gemm2(ca_o, C_, d_in[31], (size_t)t * C_ * C_, d_in[32], tC, clsy, B_, C_, C_, 0);
        k_resadd2<<<48, 256, 0, stream>>>(cls, clsy, d_in[39], tC, B_ * C_, flg);
        k_layernorm2<<<B_, 256, 0, stream>>>(cls, d_in[33], tC, d_in[34], tC, clsy, flg);
        gemm2(clsy, C_, d_in[35], (size_t)t * 3072 * C_, d_in[36], (size_t)t * 3072,
              cmlp, B_, 3072, C_, 1);
        gemm2(cmlp, 3072, d_in[37], (size_t)t * C_ * 3072, d_in[38], tC, ca_o, B_, C_, 3072, 0);
        k_resadd2<<<48, 256, 0, stream>>>(cls, ca_o, d_in[40], tC, B_ * C_, flg);
    }

    // ---- final LN (cls only) + head ---------------------------------------
    k_layernorm2<<<B_, 256, 0, stream>>>(cls, d_in[41], 0, d_in[42], 0, clsy, flg);
    gemm2(clsy, C_, d_in[43], 0, d_in[44], 0, outf, B_, 1000, C_, 0);
    k_store_out<<<63, 256, 0, stream>>>(outf, d_out, B_ * 1000, flg);

    (void)n1w; (void)n1b; (void)qkvw; (void)qkvb; (void)plw; (void)plb;
    (void)pww; (void)pwb; (void)projw; (void)projb; (void)n2w; (void)n2b;
    (void)f1w; (void)f1b; (void)f2w; (void)f2b; (void)g1; (void)g2;
    (void)tn1w; (void)tn1b; (void)tqw; (void)tqb; (void)tkw; (void)tkb;
    (void)tvw; (void)tvb; (void)tprojw; (void)tprojb; (void)tn2w; (void)tn2b;
    (void)tf1w; (void)tf1b; (void)tf2w; (void)tf2b; (void)tg1; (void)tg2;
    (void)normw; (void)normb; (void)headw; (void)headb;
}

// ---------------------------------------------------------------------------
// Offset-carrying variants (element offsets are dtype-independent; the base
// pointer stays raw so ldin() scales correctly for either dtype).
// ---------------------------------------------------------------------------
__global__ __launch_bounds__(256)
void k_gemm2(const float* __restrict__ A, int lda,
             const void* __restrict__ W, size_t wo,
             const void* __restrict__ bias, size_t bo,
             float* __restrict__ Cout, int M, int N, int K, int act,
             const int* __restrict__ flg)
{
    const int isbf = flg[0];
    __shared__ float As[16][65];
    __shared__ float Ws[16][65];
    int tid = threadIdx.x;
    int tx = tid & 15, ty = tid >> 4;
    int bn = blockIdx.x * 64, bm = blockIdx.y * 64;
    float acc[4][4] = {};
    for (int k0 = 0; k0 < K; k0 += 16) {
        for (int i = tid; i < 16 * 64; i += 256) {
            int kk = i >> 6, r = i & 63;
            int gm = bm + r, gk = k0 + kk;
            As[kk][r] = (gm < M) ? A[(size_t)gm * lda + gk] : 0.f;
            int gn = bn + r;
            Ws[kk][r] = (gn < N) ? ldin(W, wo + (size_t)gn * K + gk, isbf) : 0.f;
        }
        __syncthreads();
#pragma unroll
        for (int kk = 0; kk < 16; ++kk) {
            float a[4], w[4];
#pragma unroll
            for (int i = 0; i < 4; i++) a[i] = As[kk][ty * 4 + i];
#pragma unroll
            for (int j = 0; j < 4; j++) w[j] = Ws[kk][tx * 4 + j];
#pragma unroll
            for (int i = 0; i < 4; i++)
#pragma unroll
                for (int j = 0; j < 4; j++)
                    acc[i][j] += a[i] * w[j];
        }
        __syncthreads();
    }
#pragma unroll
    for (int i = 0; i < 4; i++) {
        int gm = bm + ty * 4 + i;
        if (gm >= M) continue;
#pragma unroll
        for (int j = 0; j < 4; j++) {
            int gn = bn + tx * 4 + j;
            if (gn >= N) continue;
            float v = acc[i][j] + ldin(bias, bo + gn, isbf);
            if (act == 1) v = 0.5f * v * (1.0f + erff(v * 0.70710678118654752f));
            Cout[(size_t)gm * N + gn] = v;
        }
    }
}

__global__ __launch_bounds__(256)
void k_layernorm2(const float* __restrict__ X, const void* __restrict__ w, size_t wo,
                  const void* __restrict__ b, size_t bo, float* __restrict__ Y,
                  const int* __restrict__ flg)
{
    const int isbf = flg[0];
    __shared__ float red[4];
    __shared__ float stat[2];
    int row = blockIdx.x, t = threadIdx.x;
    const float* x = X + (size_t)row * C_;
    float* y = Y + (size_t)row * C_;
    float a0 = x[t], a1 = x[t + 256], a2 = x[t + 512];
    float s = a0 + a1 + a2;
#pragma unroll
    for (int off = 32; off > 0; off >>= 1) s += __shfl_down(s, off);
    if ((t & 63) == 0) red[t >> 6] = s;
    __syncthreads();
    if (t == 0) stat[0] = (red[0] + red[1] + red[2] + red[3]) * (1.f / 768.f);
    __syncthreads();
    float m = stat[0];
    float d0 = a0 - m, d1 = a1 - m, d2 = a2 - m;
    float s2 = d0 * d0 + d1 * d1 + d2 * d2;
#pragma unroll
    for (int off = 32; off > 0; off >>= 1) s2 += __shfl_down(s2, off);
    if ((t & 63) == 0) red[t >> 6] = s2;
    __syncthreads();
    if (t == 0) stat[1] = rsqrtf((red[0] + red[1] + red[2] + red[3]) * (1.f / 768.f) + 1e-6f);
    __syncthreads();
    float r = stat[1];
    y[t]       = d0 * r * ldin(w, wo + t, isbf)       + ldin(b, bo + t, isbf);
    y[t + 256] = d1 * r * ldin(w, wo + t + 256, isbf) + ldin(b, bo + t + 256, isbf);
    y[t + 512] = d2 * r * ldin(w, wo + t + 512, isbf) + ldin(b, bo + t + 512, isbf);
}

__global__ __launch_bounds__(256)
void k_layernorm_cat2(const float* __restrict__ cls, const float* __restrict__ h,
                      const void* __restrict__ w, size_t wo,
                      const void* __restrict__ b, size_t bo,
                      float* __restrict__ Y, const int* __restrict__ flg)
{
    const int isbf = flg[0];
    __shared__ float red[4];
    __shared__ float stat[2];
    int row = blockIdx.x, t = threadIdx.x;
    int bb = row / 197, tkn = row % 197;
    const float* x = (tkn == 0) ? (cls + (size_t)bb * C_)
                                : (h + ((size_t)bb * NP_ + (tkn - 1)) * C_);
    float* y = Y + (size_t)row * C_;
    float a0 = x[t], a1 = x[t + 256], a2 = x[t + 512];
    float s = a0 + a1 + a2;
#pragma unroll
    for (int off = 32; off > 0; off >>= 1) s += __shfl_down(s, off);
    if ((t & 63) == 0) red[t >> 6] = s;
    __syncthreads();
    if (t == 0) stat[0] = (red[0] + red[1] + red[2] + red[3]) * (1.f / 768.f);
    __syncthreads();
    float m = stat[0];
    float d0 = a0 - m, d1 = a1 - m, d2 = a2 - m;
    float s2 = d0 * d0 + d1 * d1 + d2 * d2;
#pragma unroll
    for (int off = 32; off > 0; off >>= 1) s2 += __shfl_down(s2, off);
    if ((t & 63) == 0) red[t >> 6] = s2;
    __syncthreads();
    if (t == 0) stat[1] = rsqrtf((red[0] + red[1] + red[2] + red[3]) * (1.f / 768.f) + 1e-6f);
    __syncthreads();
    float r = stat[1];
    y[t]       = d0 * r * ldin(w, wo + t, isbf)       + ldin(b, bo + t, isbf);
    y[t + 256] = d1 * r * ldin(w, wo + t + 256, isbf) + ldin(b, bo + t + 256, isbf);
    y[t + 512] = d2 * r * ldin(w, wo + t + 512, isbf) + ldin(b, bo + t + 512, isbf);
}

__global__ __launch_bounds__(256)
void k_headmix2(float* __restrict__ a, const void* __restrict__ w, size_t wo,
                const void* __restrict__ bias, size_t bo, const int* __restrict__ flg)
{
    const int isbf = flg[0];
    __shared__ float ws_[144];
    __shared__ float bs_[12];
    int tid = threadIdx.x;
    if (tid < 144) ws_[tid] = ldin(w, wo + tid, isbf);
    if (tid < 12) bs_[tid] = ldin(bias, bo + tid, isbf);
    __syncthreads();
    int idx = blockIdx.x * 256 + tid;
    int b = idx / NPNP, nm = idx % NPNP;
    float* p = a + (size_t)b * H_ * NPNP + nm;
    float v[12];
#pragma unroll
    for (int hh = 0; hh < 12; hh++) v[hh] = p[(size_t)hh * NPNP];
#pragma unroll
    for (int g = 0; g < 12; g++) {
        float acc = bs_[g];
#pragma unroll
        for (int hh = 0; hh < 12; hh++) acc += ws_[g * 12 + hh] * v[hh];
        p[(size_t)g * NPNP] = acc;
    }
}

__global__ __launch_bounds__(256)
void k_resadd2(float* __restrict__ dst, const float* __restrict__ src,
               const void* __restrict__ g, size_t go, int total,
               const int* __restrict__ flg)
{
    const int isbf = flg[0];
    int i = blockIdx.x * 256 + threadIdx.x;
    if (i < total) dst[i] += ldin(g, go + (size_t)(i % C_), isbf) * src[i];
}

// Round 4
// 7080.103 us; speedup vs baseline: 4.1883x; 4.1883x over previous
//
#include <hip/hip_runtime.h>
#include <hip/hip_bf16.h>

using bf16 = __hip_bfloat16;
typedef short short8 __attribute__((ext_vector_type(8)));
typedef float floatx4 __attribute__((ext_vector_type(4)));

#define B_   16
#define C_   768
#define NP_  196
#define H_   12
#define NPNP 38416   // 196*196

static __device__ __forceinline__ float b2f(bf16 v) { return __bfloat162float(v); }
static __device__ __forceinline__ unsigned short f2bfbits(float f) {
    bf16 t = __float2bfloat16(f);
    return *(unsigned short*)&t;
}

// ---------------------------------------------------------------------------
// Batched MFMA GEMM:  C[z][m][n] = act( scale * sum_k A[z][m][k]*W[z][n][k] + bias[n] )
// A bf16 row-major. W bf16 (wfp=0) or fp32 (wfp=1, converted to bf16 in
// staging). bias fp32 or null. K multiple of 32, lda/ldw multiple of 8.
// Output fp32 (outbf=0) or bf16 (outbf=1). Batch z: coff = (z/BI)*sCo+(z%BI)*sCi.
// Tile 128x128, 256 thr = 4 waves (2x2), each wave 4x4 of 16x16x32 MFMA.
// ---------------------------------------------------------------------------
__global__ __launch_bounds__(256)
void k_mgemm(const bf16* __restrict__ A, long long sA, int lda,
             const void* __restrict__ W, long long sW, int ldw, int wfp,
             char* __restrict__ Cb, long long sCo, long long sCi, int BI, int ldc,
             const float* __restrict__ bias,
             int M, int N, int K, float scale, int act, int outbf)
{
    __shared__ unsigned short As[128 * 40];   // stride 40 elems (80B)
    __shared__ unsigned short Ws[128 * 40];

    const int z = blockIdx.z;
    const unsigned short* Ag = (const unsigned short*)A + (size_t)z * sA;

    const int tid = threadIdx.x;
    const int lane = tid & 63, w = tid >> 6;
    const int wm = w >> 1, wn = w & 1;
    const int p = lane & 15, q = lane >> 4;
    const int bm = blockIdx.y * 128, bn = blockIdx.x * 128;

    const int srow = tid >> 2;            // 0..63
    const int c8 = (tid & 3) * 8;         // k-chunk offset in elements

    floatx4 acc[4][4] = {};

    for (int k0 = 0; k0 < K; k0 += 32) {
        __syncthreads();
#pragma unroll
        for (int it = 0; it < 2; it++) {
            int r = srow + it * 64;
            int am = bm + r; am = (am < M) ? am : (M - 1);
            short8 av = *(const short8*)(Ag + (size_t)am * lda + k0 + c8);
            *(short8*)(&As[r * 40 + c8]) = av;
            int wr = bn + r; wr = (wr < N) ? wr : (N - 1);
            if (wfp) {
                const float* wp = (const float*)W + (size_t)z * sW
                                  + (size_t)wr * ldw + k0 + c8;
                floatx4 w0 = *(const floatx4*)wp;
                floatx4 w1 = *(const floatx4*)(wp + 4);
                unsigned short* d = &Ws[r * 40 + c8];
#pragma unroll
                for (int j = 0; j < 4; j++) d[j]     = f2bfbits(w0[j]);
#pragma unroll
                for (int j = 0; j < 4; j++) d[4 + j] = f2bfbits(w1[j]);
            } else {
                const unsigned short* wp = (const unsigned short*)W
                                           + (size_t)z * sW + (size_t)wr * ldw + k0 + c8;
                *(short8*)(&Ws[r * 40 + c8]) = *(const short8*)wp;
            }
        }
        __syncthreads();
        short8 af[4], wf[4];
#pragma unroll
        for (int i = 0; i < 4; i++)
            af[i] = *(const short8*)(&As[(wm * 64 + i * 16 + p) * 40 + q * 8]);
#pragma unroll
        for (int j = 0; j < 4; j++)
            wf[j] = *(const short8*)(&Ws[(wn * 64 + j * 16 + p) * 40 + q * 8]);
#pragma unroll
        for (int i = 0; i < 4; i++)
#pragma unroll
            for (int j = 0; j < 4; j++)
                acc[i][j] = __builtin_amdgcn_mfma_f32_16x16x32_bf16(af[i], wf[j], acc[i][j], 0, 0, 0);
    }

    const long long coff = (long long)(z / BI) * sCo + (long long)(z % BI) * sCi;
    float* Cf = (float*)Cb + coff;
    bf16*  Ch = (bf16*)Cb + coff;
#pragma unroll
    for (int i = 0; i < 4; i++) {
#pragma unroll
        for (int r = 0; r < 4; r++) {
            int gm = bm + wm * 64 + i * 16 + q * 4 + r;
            if (gm >= M) continue;
#pragma unroll
            for (int j = 0; j < 4; j++) {
                int gn = bn + wn * 64 + j * 16 + p;
                if (gn >= N) continue;
                float v = acc[i][j][r] * scale;
                if (bias) v += bias[gn];
                if (act) v = 0.5f * v * (1.0f + erff(v * 0.70710678118654752f));
                if (outbf) Ch[(size_t)gm * ldc + gn] = __float2bfloat16(v);
                else       Cf[(size_t)gm * ldc + gn] = v;
            }
        }
    }
}

// ---------------------------------------------------------------------------
__global__ __launch_bounds__(256)
void k_patch_gather(const float* __restrict__ x, bf16* __restrict__ p)
{
    int idx = blockIdx.x * 256 + threadIdx.x;            // 2,408,448
    int k = idx % 768;
    int n = (idx / 768) % NP_;
    int b = idx / (768 * NP_);
    int c = k >> 8, r = k & 255;
    int py = r >> 4, px = r & 15;
    int gy = n / 14, gx = n % 14;
    p[idx] = __float2bfloat16(x[(((size_t)b * 3 + c) * 224 + gy * 16 + py) * 224 + gx * 16 + px]);
}

__global__ __launch_bounds__(256)
void k_addpos(float* __restrict__ h, const float* __restrict__ pos)
{
    int idx = blockIdx.x * 256 + threadIdx.x;            // 2,408,448
    h[idx] += pos[idx % (NP_ * C_)];
}

// LayerNorm over C=768: fp32 in -> bf16 out. One block per row.
__device__ __forceinline__ void ln_row(const float* __restrict__ x,
                                       const float* __restrict__ w,
                                       const float* __restrict__ b,
                                       bf16* __restrict__ y, int t,
                                       float* red, float* stat)
{
    float a0 = x[t], a1 = x[t + 256], a2 = x[t + 512];
    float s = a0 + a1 + a2;
#pragma unroll
    for (int off = 32; off > 0; off >>= 1) s += __shfl_down(s, off);
    if ((t & 63) == 0) red[t >> 6] = s;
    __syncthreads();
    if (t == 0) stat[0] = (red[0] + red[1] + red[2] + red[3]) * (1.f / 768.f);
    __syncthreads();
    float m = stat[0];
    float d0 = a0 - m, d1 = a1 - m, d2 = a2 - m;
    float s2 = d0 * d0 + d1 * d1 + d2 * d2;
#pragma unroll
    for (int off = 32; off > 0; off >>= 1) s2 += __shfl_down(s2, off);
    if ((t & 63) == 0) red[t >> 6] = s2;
    __syncthreads();
    if (t == 0) stat[1] = rsqrtf((red[0] + red[1] + red[2] + red[3]) * (1.f / 768.f) + 1e-6f);
    __syncthreads();
    float r = stat[1];
    y[t]       = __float2bfloat16(d0 * r * w[t]       + b[t]);
    y[t + 256] = __float2bfloat16(d1 * r * w[t + 256] + b[t + 256]);
    y[t + 512] = __float2bfloat16(d2 * r * w[t + 512] + b[t + 512]);
}

__global__ __launch_bounds__(256)
void k_ln(const float* __restrict__ X, const float* __restrict__ w,
          const float* __restrict__ b, bf16* __restrict__ Y)
{
    __shared__ float red[4];
    __shared__ float stat[2];
    int row = blockIdx.x;
    ln_row(X + (size_t)row * C_, w, b, Y + (size_t)row * C_, threadIdx.x, red, stat);
}

__global__ __launch_bounds__(256)
void k_ln_cat(const float* __restrict__ cls, const float* __restrict__ h,
              const float* __restrict__ w, const float* __restrict__ b,
              bf16* __restrict__ Y)
{
    __shared__ float red[4];
    __shared__ float stat[2];
    int row = blockIdx.x;
    int bb = row / 197, tkn = row % 197;
    const float* src = (tkn == 0) ? (cls + (size_t)bb * C_)
                                  : (h + ((size_t)bb * NP_ + (tkn - 1)) * C_);
    ln_row(src, w, b, Y + (size_t)row * C_, threadIdx.x, red, stat);
}

// qkv bf16 [3136x2304] -> Qb,Kb [z][196][64]; z = b*12+h
__global__ __launch_bounds__(256)
void k_splitqk(const bf16* __restrict__ qkv, bf16* __restrict__ Qb, bf16* __restrict__ Kb)
{
    int idx = blockIdx.x * 256 + threadIdx.x;            // 2,408,448
    int d = idx & 63;
    int rest = idx >> 6;
    int n = rest % NP_, zz = rest / NP_;
    int b = zz / H_, hh = zz % H_;
    size_t src = ((size_t)b * NP_ + n) * 2304 + hh * 64 + d;
    Qb[idx] = qkv[src];
    Kb[idx] = qkv[src + 768];
}

// V transposed: VT[z][d][m] (m padded 196->224 with 0)
__global__ __launch_bounds__(256)
void k_splitv(const bf16* __restrict__ qkv, bf16* __restrict__ VT)
{
    int idx = blockIdx.x * 256 + threadIdx.x;            // 2,752,512
    int m = idx % 224;
    int rest = idx / 224;
    int d = rest & 63, zz = rest >> 6;
    int b = zz / H_, hh = zz % H_;
    bf16 v = __float2bfloat16(0.f);
    if (m < NP_) v = qkv[((size_t)b * NP_ + m) * 2304 + 1536 + hh * 64 + d];
    VT[idx] = v;
}

// in-place pre-softmax head mix on S fp32 [b][h][196][196]
__global__ __launch_bounds__(256)
void k_headmix_pre(float* __restrict__ a, const float* __restrict__ w,
                   const float* __restrict__ bias)
{
    __shared__ float ws_[144];
    __shared__ float bs_[12];
    int tid = threadIdx.x;
    if (tid < 144) ws_[tid] = w[tid];
    if (tid < 12) bs_[tid] = bias[tid];
    __syncthreads();
    int idx = blockIdx.x * 256 + tid;                    // 614,656
    int b = idx / NPNP, nm = idx % NPNP;
    float* pp = a + (size_t)b * H_ * NPNP + nm;
    float v[12];
#pragma unroll
    for (int hh = 0; hh < 12; hh++) v[hh] = pp[(size_t)hh * NPNP];
#pragma unroll
    for (int g = 0; g < 12; g++) {
        float acc = bs_[g];
#pragma unroll
        for (int hh = 0; hh < 12; hh++) acc += ws_[g * 12 + hh] * v[hh];
        pp[(size_t)g * NPNP] = acc;
    }
}

// post-softmax head mix: reads S fp32, writes P bf16 [z][196][224]
__global__ __launch_bounds__(256)
void k_headmix_post(const float* __restrict__ a, const float* __restrict__ w,
                    const float* __restrict__ bias, bf16* __restrict__ P)
{
    __shared__ float ws_[144];
    __shared__ float bs_[12];
    int tid = threadIdx.x;
    if (tid < 144) ws_[tid] = w[tid];
    if (tid < 12) bs_[tid] = bias[tid];
    __syncthreads();
    int idx = blockIdx.x * 256 + tid;
    int b = idx / NPNP, nm = idx % NPNP;
    int n = nm / NP_, m = nm % NP_;
    const float* pp = a + (size_t)b * H_ * NPNP + nm;
    float v[12];
#pragma unroll
    for (int hh = 0; hh < 12; hh++) v[hh] = pp[(size_t)hh * NPNP];
#pragma unroll
    for (int g = 0; g < 12; g++) {
        float acc = bs_[g];
#pragma unroll
        for (int hh = 0; hh < 12; hh++) acc += ws_[g * 12 + hh] * v[hh];
        P[(((size_t)(b * H_ + g)) * NP_ + n) * 224 + m] = __float2bfloat16(acc);
    }
}

// softmax over last axis (196); one wave per row, fp32 in-place
__global__ __launch_bounds__(64)
void k_softmax(float* __restrict__ attn)
{
    size_t row = blockIdx.x;                             // 192*196
    float* pp = attn + row * NP_;
    int t = threadIdx.x;
    float v[4];
    float mx = -1e30f;
#pragma unroll
    for (int i = 0; i < 4; i++) {
        int m = t + 64 * i;
        v[i] = (m < NP_) ? pp[m] : -1e30f;
        mx = fmaxf(mx, v[i]);
    }
#pragma unroll
    for (int off = 32; off > 0; off >>= 1) mx = fmaxf(mx, __shfl_down(mx, off));
    mx = __shfl(mx, 0);
    float s = 0.f;
#pragma unroll
    for (int i = 0; i < 4; i++) {
        int m = t + 64 * i;
        if (m < NP_) { v[i] = expf(v[i] - mx); s += v[i]; }
    }
#pragma unroll
    for (int off = 32; off > 0; off >>= 1) s += __shfl_down(s, off);
    s = __shfl(s, 0);
    float inv = 1.0f / s;
#pragma unroll
    for (int i = 0; i < 4; i++) {
        int m = t + 64 * i;
        if (m < NP_) pp[m] = v[i] * inv;
    }
}

__global__ __launch_bounds__(256)
void k_resadd(float* __restrict__ dst, const float* __restrict__ src,
              const float* __restrict__ g, int total)
{
    int i = blockIdx.x * 256 + threadIdx.x;
    if (i < total) dst[i] += g[i % C_] * src[i];
}

// class-attention: q fp32 [B,C], k/v bf16 [B*197,C] -> o bf16 [B,C]
__global__ __launch_bounds__(256)
void k_ca_attn(const float* __restrict__ q, const bf16* __restrict__ kb,
               const bf16* __restrict__ vb, bf16* __restrict__ o)
{
    __shared__ float sc[200];
    __shared__ float qs[64];
    __shared__ float inv_s;
    int b = blockIdx.x / H_, hh = blockIdx.x % H_;
    int t = threadIdx.x;
    if (t < 64) qs[t] = q[b * C_ + hh * 64 + t] * 0.125f;
    __syncthreads();
    if (t < 197) {
        const bf16* kp = kb + ((size_t)b * 197 + t) * C_ + hh * 64;
        float s = 0.f;
#pragma unroll 8
        for (int d = 0; d < 64; d++) s += qs[d] * b2f(kp[d]);
        sc[t] = s;
    }
    __syncthreads();
    if (t == 0) {
        float mx = -1e30f;
        for (int m = 0; m < 197; m++) mx = fmaxf(mx, sc[m]);
        float sum = 0.f;
        for (int m = 0; m < 197; m++) { float e = expf(sc[m] - mx); sc[m] = e; sum += e; }
        inv_s = 1.0f / sum;
    }
    __syncthreads();
    if (t < 64) {
        const bf16* vp = vb + (size_t)b * 197 * C_ + hh * 64 + t;
        float acc = 0.f;
        for (int m = 0; m < 197; m++) acc += sc[m] * b2f(vp[(size_t)m * C_]);
        o[b * C_ + hh * 64 + t] = __float2bfloat16(acc * inv_s);
    }
}

__global__ __launch_bounds__(256)
void k_bcast_cls(const float* __restrict__ ct, float* __restrict__ cls)
{
    int i = blockIdx.x * 256 + threadIdx.x;              // 12288
    if (i < B_ * C_) cls[i] = ct[i % C_];
}

__global__ __launch_bounds__(256)
void k_zero(float* __restrict__ p, int n)
{
    int i = blockIdx.x * 256 + threadIdx.x;
    if (i < n) p[i] = 0.f;
}

// ---------------------------------------------------------------------------
extern "C" void kernel_launch(void* const* d_in, const int* in_sizes, int n_in,
                              void* d_out, int out_size, void* d_ws, size_t ws_size,
                              hipStream_t stream)
{
    const float* in_x    = (const float*)d_in[0];
    const float* patch_w = (const float*)d_in[1];
    const float* patch_b = (const float*)d_in[2];
    const float* cls_tok = (const float*)d_in[3];
    const float* pos_emb = (const float*)d_in[4];
    const float* n1w = (const float*)d_in[5],  *n1b = (const float*)d_in[6];
    const float* qkvw = (const float*)d_in[7], *qkvb = (const float*)d_in[8];
    const float* plw = (const float*)d_in[9],  *plb = (const float*)d_in[10];
    const float* pww = (const float*)d_in[11], *pwb = (const float*)d_in[12];
    const float* projw = (const float*)d_in[13], *projb = (const float*)d_in[14];
    const float* n2w = (const float*)d_in[15], *n2b = (const float*)d_in[16];
    const float* f1w = (const float*)d_in[17], *f1b = (const float*)d_in[18];
    const float* f2w = (const float*)d_in[19], *f2b = (const float*)d_in[20];
    const float* g1 = (const float*)d_in[21],  *g2 = (const float*)d_in[22];
    const float* tn1w = (const float*)d_in[23], *tn1b = (const float*)d_in[24];
    const float* tqw = (const float*)d_in[25], *tqb = (const float*)d_in[26];
    const float* tkw = (const float*)d_in[27], *tkb = (const float*)d_in[28];
    const float* tvw = (const float*)d_in[29], *tvb = (const float*)d_in[30];
    const float* tprojw = (const float*)d_in[31], *tprojb = (const float*)d_in[32];
    const float* tn2w = (const float*)d_in[33], *tn2b = (const float*)d_in[34];
    const float* tf1w = (const float*)d_in[35], *tf1b = (const float*)d_in[36];
    const float* tf2w = (const float*)d_in[37], *tf2b = (const float*)d_in[38];
    const float* tg1 = (const float*)d_in[39], *tg2 = (const float*)d_in[40];
    const float* normw = (const float*)d_in[41], *normb = (const float*)d_in[42];
    const float* headw = (const float*)d_in[43], *headb = (const float*)d_in[44];
    (void)in_sizes; (void)n_in; (void)out_size; (void)ws_size;

    const int M = B_ * NP_;          // 3136
    char* wsb = (char*)d_ws;
    // ---- workspace layout (bytes) ----
    float* h    = (float*)(wsb + 0);                 //  9,633,792 B fp32 residual
    bf16*  yB   = (bf16*)(wsb + 9633792);            //  4,816,896 B bf16 LN out
    char*  BIG  = wsb + 14450688;                    // 29,503,488 B multi-use
    bf16*  Qb   = (bf16*)(wsb + 43954176);           //  4,816,896
    bf16*  Kb   = (bf16*)(wsb + 48771072);           //  4,816,896
    bf16*  VT   = (bf16*)(wsb + 53587968);           //  5,505,024
    bf16*  P    = (bf16*)(wsb + 59092992);           // 16,859,136
    bf16*  oB   = (bf16*)(wsb + 75952128);           //  4,816,896 -> end 80,769,024
    // BIG aliases
    bf16*  pbuf = (bf16*)BIG;                        // patches [3136x768]
    bf16*  qkvB = (bf16*)BIG;                        // [3136x2304] bf16
    float* S    = (float*)BIG;                       // [192][196][196] fp32
    bf16*  hidB = (bf16*)BIG;                        // [3136x3072] bf16
    float* f2o  = (float*)(BIG + 19267584);          // [3136x768] fp32
    float* prjo = (float*)BIG;                       // [3136x768] fp32
    // class-attention aliases
    bf16*  u    = (bf16*)BIG;                        // [3152x768]
    bf16*  kbuf = (bf16*)(BIG + 5242880);
    bf16*  vbuf = (bf16*)(BIG + 10485760);
    float* qbuf = (float*)(wsb + 43954176);          // 49,152
    bf16*  ca_o = (bf16*)(wsb + 43954176 + 65536);
    float* cprj = (float*)(wsb + 43954176 + 131072);
    bf16*  clsB = (bf16*)(wsb + 43954176 + 262144);
    bf16*  cmlp = (bf16*)(wsb + 43954176 + 327680);
    float* cls  = (float*)(wsb + 59092992);          // alias P (dead in CA phase)

    auto mg = [&](const bf16* A, long long sA, int lda,
                  const void* Wt, long long sW, int ldw, int wfp,
                  void* Cc, long long sCo, long long sCi, int BI, int ldc,
                  const float* bias, int Mm, int Nn, int Kk,
                  float scale, int act, int outbf, int batch) {
        dim3 g((Nn + 127) / 128, (Mm + 127) / 128, batch);
        k_mgemm<<<g, 256, 0, stream>>>(A, sA, lda, Wt, sW, ldw, wfp, (char*)Cc,
                                       sCo, sCi, BI, ldc, bias, Mm, Nn, Kk,
                                       scale, act, outbf);
    };

    // zero P once (tail columns 196..223 must be 0; ws re-poisoned every call)
    k_zero<<<(4214784 + 255) / 256, 256, 0, stream>>>((float*)P, 4214784);

    // ---- patch embed -------------------------------------------------------
    k_patch_gather<<<9408, 256, 0, stream>>>(in_x, pbuf);
    mg(pbuf, 0, 768, patch_w, 0, 768, 1, h, 0, 0, 1, 768, patch_b, M, 768, 768, 1.f, 0, 0, 1);
    k_addpos<<<9408, 256, 0, stream>>>(h, pos_emb);

    // ---- 12 talking-heads blocks ------------------------------------------
    for (int L = 0; L < 12; L++) {
        size_t lC = (size_t)L * C_;
        k_ln<<<M, 256, 0, stream>>>(h, n1w + lC, n1b + lC, yB);
        mg(yB, 0, 768, qkvw + (size_t)L * 2304 * 768, 0, 768, 1, qkvB, 0, 0, 1, 2304,
           qkvb + (size_t)L * 2304, M, 2304, 768, 1.f, 0, 1, 1);
        k_splitqk<<<9408, 256, 0, stream>>>(qkvB, Qb, Kb);
        k_splitv<<<10752, 256, 0, stream>>>(qkvB, VT);
        // S[z] = 0.125 * Qb[z] @ Kb[z]^T   (K=64)
        mg(Qb, 12544, 64, Kb, 12544, 64, 0, S, 38416, 0, 1, 196,
           nullptr, 196, 196, 64, 0.125f, 0, 0, 192);
        k_headmix_pre<<<2401, 256, 0, stream>>>(S, plw + L * 144, plb + L * 12);
        k_softmax<<<192 * NP_, 64, 0, stream>>>(S);
        k_headmix_post<<<2401, 256, 0, stream>>>(S, pww + L * 144, pwb + L * 12, P);
        // o[b][n][h*64+d] = P[z] @ V[z]  (K=224 zero-padded)
        mg(P, 43904, 224, VT, 14336, 224, 0, oB, 150528, 64, 12, 768,
           nullptr, 196, 64, 224, 1.f, 0, 1, 192);
        mg(oB, 0, 768, projw + (size_t)L * 768 * 768, 0, 768, 1, prjo, 0, 0, 1, 768,
           projb + lC, M, 768, 768, 1.f, 0, 0, 1);
        k_resadd<<<9408, 256, 0, stream>>>(h, prjo, g1 + lC, M * C_);
        k_ln<<<M, 256, 0, stream>>>(h, n2w + lC, n2b + lC, yB);
        mg(yB, 0, 768, f1w + (size_t)L * 3072 * 768, 0, 768, 1, hidB, 0, 0, 1, 3072,
           f1b + (size_t)L * 3072, M, 3072, 768, 1.f, 1, 1, 1);
        mg(hidB, 0, 3072, f2w + (size_t)L * 768 * 3072, 0, 3072, 1, f2o, 0, 0, 1, 768,
           f2b + lC, M, 768, 3072, 1.f, 0, 0, 1);
        k_resadd<<<9408, 256, 0, stream>>>(h, f2o, g2 + lC, M * C_);
    }

    // ---- 2 class-attention blocks -----------------------------------------
    k_bcast_cls<<<48, 256, 0, stream>>>(cls_tok, cls);
    const int Mu = B_ * 197;         // 3152
    for (int t = 0; t < 2; t++) {
        size_t tC = (size_t)t * C_;
        size_t tCC = (size_t)t * 768 * 768;
        size_t tFC = (size_t)t * 3072 * 768;
        k_ln_cat<<<Mu, 256, 0, stream>>>(cls, h, tn1w + tC, tn1b + tC, u);
        mg(u, 0, 197 * 768, tqw + tCC, 0, 768, 1, qbuf, 0, 0, 1, 768,
           tqb + tC, B_, 768, 768, 1.f, 0, 0, 1);
        mg(u, 0, 768, tkw + tCC, 0, 768, 1, kbuf, 0, 0, 1, 768,
           tkb + tC, Mu, 768, 768, 1.f, 0, 1, 1);
        mg(u, 0, 768, tvw + tCC, 0, 768, 1, vbuf, 0, 0, 1, 768,
           tvb + tC, Mu, 768, 768, 1.f, 0, 1, 1);
        k_ca_attn<<<B_ * H_, 256, 0, stream>>>(qbuf, kbuf, vbuf, ca_o);
        mg(ca_o, 0, 768, tprojw + tCC, 0, 768, 1, cprj, 0, 0, 1, 768,
           tprojb + tC, B_, 768, 768, 1.f, 0, 0, 1);
        k_resadd<<<48, 256, 0, stream>>>(cls, cprj, tg1 + tC, B_ * C_);
        k_ln<<<B_, 256, 0, stream>>>(cls, tn2w + tC, tn2b + tC, clsB);
        mg(clsB, 0, 768, tf1w + tFC, 0, 768, 1, cmlp, 0, 0, 1, 3072,
           tf1b + (size_t)t * 3072, B_, 3072, 768, 1.f, 1, 1, 1);
        mg(cmlp, 0, 3072, tf2w + tFC, 0, 3072, 1, cprj, 0, 0, 1, 768,
           tf2b + tC, B_, 768, 3072, 1.f, 0, 0, 1);
        k_resadd<<<48, 256, 0, stream>>>(cls, cprj, tg2 + tC, B_ * C_);
    }

    // ---- final LN (cls only) + head directly to d_out (fp32) --------------
    k_ln<<<B_, 256, 0, stream>>>(cls, normw, normb, clsB);
    mg(clsB, 0, 768, headw, 0, 768, 1, d_out, 0, 0, 1, 1000,
       headb, B_, 1000, 768, 1.f, 0, 0, 1);
}